// Round 3
// baseline (858.164 us; speedup 1.0000x reference)
//
#include <hip/hip_runtime.h>
#include <hip/hip_bf16.h>

// Problem: B=1M rows, obs[B,64] fp32 -> two fused 64->128->64 MLPs, route by
// one-hot obs[:,2:4]. Strategy: both-branch bf16 MFMA, fp32 bias/accum,
// per-lane routing mask on h, zero-LDS layer1->layer2 handoff via a
// j-permutation baked into W2^T storage.
//
// R1 fix: layer-1 second K-half A-frag was read at byte 32+q*16; K in [32,64)
// of the 128-byte W1^T row lives at 64+q*16. (Caused 6.1e-3 absmax.)
// R2: resubmit unchanged (R1 never ran - GPU acquisition timeout).

#define B_ROWS  (1 << 20)
#define IN_DIM  64
#define HID     128
#define FEAT    64
#define NBLK    512
#define NITER   (B_ROWS / (128 * NBLK))   // = 16 row-blocks of 128 per block

typedef __attribute__((ext_vector_type(4))) float f32x4;
typedef __attribute__((ext_vector_type(2))) float f32x2;
typedef __attribute__((ext_vector_type(8))) short s16x8;

static __device__ __forceinline__ short f2bf(float f) {
    __hip_bfloat16 h = __float2bfloat16(f);   // RNE
    short s;
    __builtin_memcpy(&s, &h, 2);
    return s;
}

// ---------------------------------------------------------------------------
// Kernel A: fuse weights into d_ws.
//  w1t: [2][128 j][64 k] bf16, byte (k*2) ^ ((j&7)<<4) within 128B rows
//  w2t: [2][64 c][128 slots] bf16, slot = phi-permuted j, swizzled per row
//  b1f: [2][128] fp32 ; b2f: [2][64] fp32
// phi: slot (8q+i) within a 32-block holds j = 32blk + (i<4 ? 4q+i : 16+4q+i-4)
// ---------------------------------------------------------------------------
__global__ void fuse_weights(
    const float* __restrict__ W1b, const float* __restrict__ b1b,
    const float* __restrict__ W2b, const float* __restrict__ b2b,
    const float* __restrict__ W1c, const float* __restrict__ b1c,
    const float* __restrict__ W2c, const float* __restrict__ b2c,
    const float* __restrict__ W1p, const float* __restrict__ b1p,
    const float* __restrict__ W2p, const float* __restrict__ b2p,
    short* __restrict__ w1t, short* __restrict__ w2t,
    float* __restrict__ b1f, float* __restrict__ b2f)
{
    int t  = blockIdx.x * blockDim.x + threadIdx.x;
    int nt = gridDim.x * blockDim.x;

    // W1^T
    for (int idx = t; idx < 2 * HID * IN_DIM; idx += nt) {
        int e = idx >> 13;
        int r = idx & 8191;
        int j = r >> 6;          // 0..127 (hidden)
        int k = r & 63;          // 0..63  (input)
        const float* Wx = e ? W1c : W1b;
        float v = Wx[k * HID + j] * W1p[k * HID + j];
        int off = (k * 2) ^ ((j & 7) << 4);
        *(short*)((char*)w1t + e * 16384 + j * 128 + off) = f2bf(v);
    }
    // W2^T with phi permutation
    for (int idx = t; idx < 2 * FEAT * HID; idx += nt) {
        int e = idx >> 13;
        int r = idx & 8191;
        int c = r >> 7;          // 0..63  (out feature)
        int j = r & 127;         // 0..127 (hidden)
        const float* Wx = e ? W2c : W2b;
        float v = Wx[j * FEAT + c] * W2p[j * FEAT + c];
        int jm  = j & 31, blk = j >> 5;
        int pos;
        if (jm < 16) pos = ((jm >> 2) * 8) + (jm & 3);
        else { int jj = jm - 16; pos = ((jj >> 2) * 8) + 4 + (jj & 3); }
        pos += blk * 32;
        int off = (pos * 2) ^ ((c & 7) << 4);
        *(short*)((char*)w2t + e * 16384 + c * 256 + off) = f2bf(v);
    }
    for (int idx = t; idx < 2 * HID; idx += nt) {
        int e = idx >> 7, j = idx & 127;
        b1f[idx] = (e ? b1c[j] : b1b[j]) + b1p[j];
    }
    for (int idx = t; idx < 2 * FEAT; idx += nt) {
        int e = idx >> 6, c = idx & 63;
        b2f[idx] = (e ? b2c[c] : b2b[c]) + b2p[c];
    }
}

// ---------------------------------------------------------------------------
// Main kernel
// ---------------------------------------------------------------------------
struct XBuf {
    f32x4 x[2][2][2];   // [rt][ks][half]  (B1-frag fp32 staging)
    f32x2 fl[2];        // [rt] obs cols 2,3 for row (base+rt*16+cl)
};

static __device__ __forceinline__ void load_x(
    const float* __restrict__ obs, int rowbase, int cl, int q, XBuf& b)
{
#pragma unroll
    for (int rt = 0; rt < 2; ++rt) {
        const char* rp = (const char*)obs + (size_t)(rowbase + rt * 16 + cl) * 256;
#pragma unroll
        for (int ks = 0; ks < 2; ++ks) {
            b.x[rt][ks][0] = *(const f32x4*)(rp + ks * 128 + q * 32);
            b.x[rt][ks][1] = *(const f32x4*)(rp + ks * 128 + q * 32 + 16);
        }
        b.fl[rt] = *(const f32x2*)(rp + 8);
    }
}

static __device__ __forceinline__ void compute_tile(
    const XBuf& xb, int rowbase, int cl, int q, int sw,
    const short* s_w1, const short* s_w2,
    const float* __restrict__ b1f, const float* __restrict__ b2f,
    float* __restrict__ out)
{
    const f32x4 zero = {0.f, 0.f, 0.f, 0.f};

    // X -> bf16 B-frags
    s16x8 xf[2][2];
#pragma unroll
    for (int rt = 0; rt < 2; ++rt) {
#pragma unroll
        for (int ks = 0; ks < 2; ++ks) {
            s16x8 v;
#pragma unroll
            for (int h = 0; h < 2; ++h) {
                f32x4 f = xb.x[rt][ks][h];
                v[h * 4 + 0] = f2bf(f.x);
                v[h * 4 + 1] = f2bf(f.y);
                v[h * 4 + 2] = f2bf(f.z);
                v[h * 4 + 3] = f2bf(f.w);
            }
            xf[rt][ks] = v;
        }
    }
    bool isb[2];
#pragma unroll
    for (int rt = 0; rt < 2; ++rt)
        isb[rt] = (xb.fl[rt].x == 1.0f) && (xb.fl[rt].y == 0.0f);

    f32x4 acc2[2][4];
#pragma unroll
    for (int rt = 0; rt < 2; ++rt)
#pragma unroll
        for (int ct = 0; ct < 4; ++ct) acc2[rt][ct] = zero;

#pragma unroll
    for (int e = 0; e < 2; ++e) {
        // ---- layer 1: D1 = W1f^T-tile * X^T  => H^T fragments in regs
        f32x4 acc1[2][8];
#pragma unroll
        for (int jt = 0; jt < 8; ++jt) {
            const char* rowp = (const char*)s_w1 + e * 16384 + (jt * 16 + cl) * 128;
            s16x8 a0 = *(const s16x8*)(rowp + ((q * 16) ^ sw));
            s16x8 a1 = *(const s16x8*)(rowp + ((64 + q * 16) ^ sw));   // K in [32,64) at bytes 64..127
#pragma unroll
            for (int rt = 0; rt < 2; ++rt) {
                f32x4 acc = __builtin_amdgcn_mfma_f32_16x16x32_bf16(a0, xf[rt][0], zero, 0, 0, 0);
                acc1[rt][jt] = __builtin_amdgcn_mfma_f32_16x16x32_bf16(a1, xf[rt][1], acc, 0, 0, 0);
            }
        }
        // ---- bias + relu + route-mask + cvt; pack pairs of j-tiles into K=32 frags
        s16x8 hc[2][4];
#pragma unroll
        for (int rt = 0; rt < 2; ++rt) {
            bool keep = (e == 0) ? isb[rt] : !isb[rt];
#pragma unroll
            for (int jt = 0; jt < 8; ++jt) {
                f32x4 bv = *(const f32x4*)(b1f + e * 128 + jt * 16 + q * 4);
                f32x4 a  = acc1[rt][jt];
#pragma unroll
                for (int r = 0; r < 4; ++r) {
                    float t = fmaxf(a[r] + bv[r], 0.0f);
                    t = keep ? t : 0.0f;
                    hc[rt][jt >> 1][(jt & 1) * 4 + r] = f2bf(t);
                }
            }
        }
        // ---- layer 2: D2 += W2f^T-tile * H^T  (phi baked into s_w2)
#pragma unroll
        for (int ct = 0; ct < 4; ++ct) {
            const char* rowp2 = (const char*)s_w2 + e * 16384 + (ct * 16 + cl) * 256;
#pragma unroll
            for (int ks2 = 0; ks2 < 4; ++ks2) {
                s16x8 a2 = *(const s16x8*)(rowp2 + ((ks2 * 64 + q * 16) ^ sw));
#pragma unroll
                for (int rt = 0; rt < 2; ++rt)
                    acc2[rt][ct] = __builtin_amdgcn_mfma_f32_16x16x32_bf16(
                        a2, hc[rt][ks2], acc2[rt][ct], 0, 0, 0);
            }
        }
    }
    // ---- epilogue: + selected b2, dwordx4 stores (c = 16ct+4q+reg contiguous)
#pragma unroll
    for (int rt = 0; rt < 2; ++rt) {
        const float* b2sel = b2f + (isb[rt] ? 0 : 64);
        char* orow = (char*)out + (size_t)(rowbase + rt * 16 + cl) * 256;
#pragma unroll
        for (int ct = 0; ct < 4; ++ct) {
            f32x4 bv = *(const f32x4*)(b2sel + ct * 16 + q * 4);
            *(f32x4*)(orow + ct * 64 + q * 16) = acc2[rt][ct] + bv;
        }
    }
}

__global__ __launch_bounds__(256, 2) void mlp_route(
    const float* __restrict__ obs,
    const short* __restrict__ w1t, const short* __restrict__ w2t,
    const float* __restrict__ b1f, const float* __restrict__ b2f,
    float* __restrict__ out)
{
    __shared__ short s_w1[16384];   // [2][128][64] bf16, swizzled
    __shared__ short s_w2[16384];   // [2][64][128] bf16, phi+swizzled

    {   // stage weights once per block (linear copy; swizzle baked in ws)
        const f32x4* g1 = (const f32x4*)w1t;
        const f32x4* g2 = (const f32x4*)w2t;
        f32x4* d1 = (f32x4*)s_w1;
        f32x4* d2 = (f32x4*)s_w2;
        for (int i = threadIdx.x; i < 2048; i += 256) {
            d1[i] = g1[i];
            d2[i] = g2[i];
        }
    }
    __syncthreads();

    const int lane = threadIdx.x & 63;
    const int wid  = threadIdx.x >> 6;
    const int cl   = lane & 15;
    const int q    = lane >> 4;
    const int sw   = (cl & 7) << 4;

    XBuf bufA, bufB;
    // row-block rb = it*NBLK + blockIdx.x ; wave handles 32 rows of its 128
    auto rb = [&](int it) { return ((it * NBLK + (int)blockIdx.x) * 128) + wid * 32; };

    load_x(obs, rb(0), cl, q, bufA);
#pragma unroll 1
    for (int it = 0; it < NITER; it += 2) {
        load_x(obs, rb(it + 1), cl, q, bufB);
        compute_tile(bufA, rb(it), cl, q, sw, s_w1, s_w2, b1f, b2f, out);
        if (it + 2 < NITER) load_x(obs, rb(it + 2), cl, q, bufA);
        compute_tile(bufB, rb(it + 1), cl, q, sw, s_w1, s_w2, b1f, b2f, out);
    }
}

// ---------------------------------------------------------------------------
extern "C" void kernel_launch(void* const* d_in, const int* in_sizes, int n_in,
                              void* d_out, int out_size, void* d_ws, size_t ws_size,
                              hipStream_t stream)
{
    const float* obs = (const float*)d_in[0];
    const float* W1b = (const float*)d_in[1];
    const float* b1b = (const float*)d_in[2];
    const float* W2b = (const float*)d_in[3];
    const float* b2b = (const float*)d_in[4];
    const float* W1c = (const float*)d_in[5];
    const float* b1c = (const float*)d_in[6];
    const float* W2c = (const float*)d_in[7];
    const float* b2c = (const float*)d_in[8];
    const float* W1p = (const float*)d_in[9];
    const float* b1p = (const float*)d_in[10];
    const float* W2p = (const float*)d_in[11];
    const float* b2p = (const float*)d_in[12];

    short* w1t = (short*)d_ws;                          // 32 KB
    short* w2t = (short*)((char*)d_ws + 32768);         // 32 KB
    float* b1f = (float*)((char*)d_ws + 65536);         // 1 KB
    float* b2f = (float*)((char*)d_ws + 66560);         // 0.5 KB

    fuse_weights<<<64, 256, 0, stream>>>(W1b, b1b, W2b, b2b,
                                         W1c, b1c, W2c, b2c,
                                         W1p, b1p, W2p, b2p,
                                         w1t, w2t, b1f, b2f);

    mlp_route<<<NBLK, 256, 0, stream>>>(obs, w1t, w2t, b1f, b2f, (float*)d_out);
}